// Round 1
// baseline (1428.818 us; speedup 1.0000x reference)
//
#include <hip/hip_runtime.h>

#define NN 100000
#define NE 1600000
#define NBATCH 512
#define DIM 128
#define BN_EPS 1e-4f
#define NTOT (NE + NN)
#define NBAGG 2048
#define SCAN_NB 98  // ceil(NN/1024)

// ---- workspace layout (units of 4-byte elements, 64-elem aligned) ----
#define OFF_DEG     0u          // NN int
#define OFF_DINV    100032u     // NN f32
#define OFF_ROWPTR  200064u     // NN+1 int
#define OFF_CURSOR  300096u     // NN int
#define OFF_BSUM    400128u     // 128 int
#define OFF_BOFF    400256u     // 128 int
#define OFF_CSRC    400384u     // NTOT int
#define OFF_CNORM   2100416u    // NTOT f32
#define OFF_H       3800448u    // NN*128 f32
#define OFF_A       16600448u   // NN*128 f32
#define OFF_PART    29400448u   // NBAGG*256 f32
#define OFF_SC      29924736u   // 128 f32
#define OFF_SH      29924864u   // 128 f32
#define OFF_POOL    29924992u   // 512*128 f32
#define OFF_CNTB    29990528u   // 512 int

__global__ void k_deg(const int* __restrict__ dst, int* __restrict__ deg) {
    int e = blockIdx.x * blockDim.x + threadIdx.x;
    if (e < NE) atomicAdd(&deg[dst[e]], 1);
}

__global__ void k_dinv(const int* __restrict__ deg, float* __restrict__ dinv) {
    int n = blockIdx.x * blockDim.x + threadIdx.x;
    if (n < NN) dinv[n] = 1.0f / sqrtf((float)(deg[n] + 1));
}

__global__ void k_scan1(const int* __restrict__ deg, int* __restrict__ rowptr,
                        int* __restrict__ bsum) {
    __shared__ int s[1024];
    int i = blockIdx.x * 1024 + threadIdx.x;
    int v = (i < NN) ? (deg[i] + 1) : 0;
    s[threadIdx.x] = v;
    __syncthreads();
    for (int off = 1; off < 1024; off <<= 1) {
        int t = (threadIdx.x >= off) ? s[threadIdx.x - off] : 0;
        __syncthreads();
        s[threadIdx.x] += t;
        __syncthreads();
    }
    if (i < NN) rowptr[i] = s[threadIdx.x] - v;  // exclusive scan
    if (threadIdx.x == 1023) bsum[blockIdx.x] = s[1023];
}

__global__ void k_scan2(const int* __restrict__ bsum, int* __restrict__ boff,
                        int* __restrict__ rowptr) {
    if (threadIdx.x == 0 && blockIdx.x == 0) {
        int run = 0;
        for (int b = 0; b < SCAN_NB; ++b) { boff[b] = run; run += bsum[b]; }
        rowptr[NN] = run;  // == NTOT
    }
}

__global__ void k_scan3(int* __restrict__ rowptr, const int* __restrict__ boff) {
    int i = blockIdx.x * 1024 + threadIdx.x;
    if (i < NN) rowptr[i] += boff[blockIdx.x];
}

__global__ void k_self(const float* __restrict__ dinv, const int* __restrict__ rowptr,
                       int* __restrict__ cursor, int* __restrict__ csrc,
                       float* __restrict__ cnorm) {
    int n = blockIdx.x * blockDim.x + threadIdx.x;
    if (n < NN) {
        int pos = rowptr[n] + atomicAdd(&cursor[n], 1);
        csrc[pos] = n;
        float dv = dinv[n];
        cnorm[pos] = dv * dv;
    }
}

__global__ void k_fill(const int* __restrict__ src, const int* __restrict__ dst,
                       const float* __restrict__ dinv, const int* __restrict__ rowptr,
                       int* __restrict__ cursor, int* __restrict__ csrc,
                       float* __restrict__ cnorm) {
    int e = blockIdx.x * blockDim.x + threadIdx.x;
    if (e < NE) {
        int s = src[e], dd = dst[e];
        int pos = rowptr[dd] + atomicAdd(&cursor[dd], 1);
        csrc[pos] = s;
        cnorm[pos] = dinv[s] * dinv[dd];
    }
}

// h[64-row tile] = xnorm @ W ; xnorm = apply ? x*scale+shift : x  (per-feature affine = fused BN)
__launch_bounds__(256)
__global__ void k_gemm(const float* __restrict__ xin, const float* __restrict__ W,
                       const float* __restrict__ scale, const float* __restrict__ shift,
                       float* __restrict__ h, int apply) {
    __shared__ __align__(16) float xs[64 * 33];
    __shared__ __align__(16) float ws[32 * 128];
    int tid = threadIdx.x;
    int jt = tid & 31, it = tid >> 5;
    int j0 = jt * 4, r0 = it * 8;
    int rowbase = blockIdx.x * 64;
    float acc[8][4];
#pragma unroll
    for (int m = 0; m < 8; ++m)
#pragma unroll
        for (int q = 0; q < 4; ++q) acc[m][q] = 0.f;

    for (int kt = 0; kt < 128; kt += 32) {
#pragma unroll
        for (int l = 0; l < 8; ++l) {  // x tile 64x32
            int idx = tid + l * 256;
            int r = idx >> 5, c = idx & 31;
            int row = rowbase + r;
            float v = 0.f;
            if (row < NN) {
                v = xin[row * 128 + kt + c];
                if (apply) v = v * scale[kt + c] + shift[kt + c];
            }
            xs[r * 33 + c] = v;
        }
#pragma unroll
        for (int l = 0; l < 16; ++l) {  // W tile 32x128
            int idx = tid + l * 256;
            int r = idx >> 7, c = idx & 127;
            ws[r * 128 + c] = W[(kt + r) * 128 + c];
        }
        __syncthreads();
#pragma unroll 8
        for (int k = 0; k < 32; ++k) {
            float4 w4 = *(const float4*)&ws[k * 128 + j0];
#pragma unroll
            for (int m = 0; m < 8; ++m) {
                float xv = xs[(r0 + m) * 33 + k];
                acc[m][0] += xv * w4.x;
                acc[m][1] += xv * w4.y;
                acc[m][2] += xv * w4.z;
                acc[m][3] += xv * w4.w;
            }
        }
        __syncthreads();
    }
#pragma unroll
    for (int m = 0; m < 8; ++m) {
        int row = rowbase + r0 + m;
        if (row < NN) {
            float4 o;
            o.x = acc[m][0]; o.y = acc[m][1]; o.z = acc[m][2]; o.w = acc[m][3];
            *(float4*)&h[row * 128 + j0] = o;
        }
    }
}

// per-node gather-aggregate + bias + sigmoid + partial BN stats
__launch_bounds__(128)
__global__ void k_agg(const float* __restrict__ h, const int* __restrict__ rowptr,
                      const int* __restrict__ csrc, const float* __restrict__ cnorm,
                      const float* __restrict__ bias, float* __restrict__ aout,
                      float* __restrict__ part) {
    int d = threadIdx.x;
    float bv = bias[d];
    float ls = 0.f, lss = 0.f;
    for (int n = blockIdx.x; n < NN; n += gridDim.x) {
        int p = rowptr[n], e = rowptr[n + 1];
        float acc = bv;
        for (; p + 1 < e; p += 2) {
            int s0 = csrc[p], s1 = csrc[p + 1];
            float w0 = cnorm[p], w1 = cnorm[p + 1];
            float h0 = h[s0 * 128 + d];
            float h1 = h[s1 * 128 + d];
            acc += w0 * h0;
            acc += w1 * h1;
        }
        if (p < e) {
            acc += cnorm[p] * h[csrc[p] * 128 + d];
        }
        float a = 1.0f / (1.0f + __expf(-acc));
        aout[n * 128 + d] = a;
        ls += a;
        lss += a * a;
    }
    part[blockIdx.x * 256 + d] = ls;
    part[blockIdx.x * 256 + 128 + d] = lss;
}

__global__ void k_stats(const float* __restrict__ part, const float* __restrict__ gamma,
                        const float* __restrict__ beta, float* __restrict__ scale,
                        float* __restrict__ shift) {
    int d = threadIdx.x;  // 128 threads, 1 block
    float s = 0.f, ss = 0.f;
    for (int b = 0; b < NBAGG; ++b) {
        s += part[b * 256 + d];
        ss += part[b * 256 + 128 + d];
    }
    float m = s / (float)NN;
    float v = ss / (float)NN - m * m;
    float rstd = 1.0f / sqrtf(v + BN_EPS);
    float g = gamma[d];
    scale[d] = rstd * g;
    shift[d] = beta[d] - m * rstd * g;
}

// final BN + write x out + segment-pool (batch sorted: flush atomics only at boundaries)
__launch_bounds__(128)
__global__ void k_pool(const float* __restrict__ a2, const float* __restrict__ scale,
                       const float* __restrict__ shift, const int* __restrict__ batch,
                       float* __restrict__ xout, float* __restrict__ pools,
                       int* __restrict__ cntb) {
    int d = threadIdx.x;
    int n0 = blockIdx.x * 64;
    if (n0 >= NN) return;
    int n1 = min(n0 + 64, NN);
    float sc = scale[d], sh = shift[d];
    float accp = 0.f;
    int cl = 0;
    int curb = batch[n0];
    for (int n = n0; n < n1; ++n) {
        int b = batch[n];
        float xv = a2[n * 128 + d] * sc + sh;
        xout[n * 128 + d] = xv;
        if (b != curb) {
            atomicAdd(&pools[curb * 128 + d], accp);
            if (d == 0) atomicAdd(&cntb[curb], cl);
            accp = 0.f;
            cl = 0;
            curb = b;
        }
        accp += xv;
        cl++;
    }
    atomicAdd(&pools[curb * 128 + d], accp);
    if (d == 0) atomicAdd(&cntb[curb], cl);
}

__global__ void k_fin(const float* __restrict__ pools, const int* __restrict__ cntb,
                      float* __restrict__ xpool) {
    int i = blockIdx.x * blockDim.x + threadIdx.x;
    if (i < NBATCH * 128) {
        int b = i >> 7;
        float c = (float)cntb[b];
        xpool[i] = pools[i] / fmaxf(c, 1.0f);
    }
}

extern "C" void kernel_launch(void* const* d_in, const int* in_sizes, int n_in,
                              void* d_out, int out_size, void* d_ws, size_t ws_size,
                              hipStream_t stream) {
    const float* x   = (const float*)d_in[0];
    const int*   ei  = (const int*)d_in[1];
    const int*   bat = (const int*)d_in[2];
    const float* Ws  = (const float*)d_in[3];
    const float* bs  = (const float*)d_in[4];
    const float* gs  = (const float*)d_in[5];
    const float* bts = (const float*)d_in[6];
    float* out = (float*)d_out;

    float* wsf = (float*)d_ws;
    int*   deg    = (int*)wsf + OFF_DEG;
    float* dinv   = wsf + OFF_DINV;
    int*   rowptr = (int*)wsf + OFF_ROWPTR;
    int*   cursor = (int*)wsf + OFF_CURSOR;
    int*   bsum   = (int*)wsf + OFF_BSUM;
    int*   boff   = (int*)wsf + OFF_BOFF;
    int*   csrc   = (int*)wsf + OFF_CSRC;
    float* cnorm  = wsf + OFF_CNORM;
    float* hbuf   = wsf + OFF_H;
    float* abuf   = wsf + OFF_A;
    float* part   = wsf + OFF_PART;
    float* scbuf  = wsf + OFF_SC;
    float* shbuf  = wsf + OFF_SH;
    float* pools  = wsf + OFF_POOL;
    int*   cntb   = (int*)wsf + OFF_CNTB;

    const int* srcv = ei;
    const int* dstv = ei + NE;

    hipMemsetAsync(deg, 0, NN * 4, stream);
    hipMemsetAsync(cursor, 0, NN * 4, stream);
    hipMemsetAsync(pools, 0, NBATCH * 128 * 4, stream);
    hipMemsetAsync(cntb, 0, NBATCH * 4, stream);

    k_deg<<<(NE + 255) / 256, 256, 0, stream>>>(dstv, deg);
    k_dinv<<<(NN + 255) / 256, 256, 0, stream>>>(deg, dinv);
    k_scan1<<<SCAN_NB, 1024, 0, stream>>>(deg, rowptr, bsum);
    k_scan2<<<1, 1, 0, stream>>>(bsum, boff, rowptr);
    k_scan3<<<SCAN_NB, 1024, 0, stream>>>(rowptr, boff);
    k_self<<<(NN + 255) / 256, 256, 0, stream>>>(dinv, rowptr, cursor, csrc, cnorm);
    k_fill<<<(NE + 255) / 256, 256, 0, stream>>>(srcv, dstv, dinv, rowptr, cursor, csrc, cnorm);

    for (int l = 0; l < 3; ++l) {
        const float* xin = (l == 0) ? x : abuf;
        k_gemm<<<(NN + 63) / 64, 256, 0, stream>>>(xin, Ws + (size_t)l * 128 * 128,
                                                   scbuf, shbuf, hbuf, l > 0 ? 1 : 0);
        k_agg<<<NBAGG, 128, 0, stream>>>(hbuf, rowptr, csrc, cnorm, bs + l * 128, abuf, part);
        k_stats<<<1, 128, 0, stream>>>(part, gs + l * 128, bts + l * 128, scbuf, shbuf);
    }

    k_pool<<<(NN + 63) / 64, 128, 0, stream>>>(abuf, scbuf, shbuf, bat,
                                               out + NBATCH * 128, pools, cntb);
    k_fin<<<(NBATCH * 128 + 255) / 256, 256, 0, stream>>>(pools, cntb, out);
}

// Round 2
// 985.468 us; speedup vs baseline: 1.4499x; 1.4499x over previous
//
#include <hip/hip_runtime.h>

#define NN 100000
#define NE 1600000
#define NBATCH 512
#define DIM 128
#define BN_EPS 1e-4f
#define NTOT (NE + NN)
#define AGG_BLOCKS 2048
#define SCAN_NB 98  // ceil(NN/1024)

// ---- workspace layout (units of 4-byte elements, 64-elem aligned) ----
#define OFF_DEG     0u          // NN int
#define OFF_DINV    100032u     // NN f32
#define OFF_ROWPTR  200064u     // NN+1 int
#define OFF_CURSOR  300096u     // NN int
#define OFF_BSUM    400128u     // 128 int
#define OFF_BOFF    400256u     // 128 int
#define OFF_CSRC    400384u     // NTOT int
#define OFF_CNORM   2100416u    // NTOT f32
#define OFF_H       3800448u    // NN*128 f32
#define OFF_A       16600448u   // NN*128 f32
#define OFF_GSTAT   29400448u   // 3*256 f32 (per-layer sum/sumsq accumulators)
#define OFF_SC      29924736u   // 128 f32
#define OFF_SH      29924864u   // 128 f32
#define OFF_POOL    29924992u   // 512*128 f32
#define OFF_CNTB    29990528u   // 512 int

__global__ void k_deg(const int* __restrict__ dst, int* __restrict__ deg) {
    int e = blockIdx.x * blockDim.x + threadIdx.x;
    if (e < NE) atomicAdd(&deg[dst[e]], 1);
}

__global__ void k_dinv(const int* __restrict__ deg, float* __restrict__ dinv) {
    int n = blockIdx.x * blockDim.x + threadIdx.x;
    if (n < NN) dinv[n] = 1.0f / sqrtf((float)(deg[n] + 1));
}

__global__ void k_scan1(const int* __restrict__ deg, int* __restrict__ rowptr,
                        int* __restrict__ bsum) {
    __shared__ int s[1024];
    int i = blockIdx.x * 1024 + threadIdx.x;
    int v = (i < NN) ? (deg[i] + 1) : 0;
    s[threadIdx.x] = v;
    __syncthreads();
    for (int off = 1; off < 1024; off <<= 1) {
        int t = (threadIdx.x >= off) ? s[threadIdx.x - off] : 0;
        __syncthreads();
        s[threadIdx.x] += t;
        __syncthreads();
    }
    if (i < NN) rowptr[i] = s[threadIdx.x] - v;  // exclusive scan
    if (threadIdx.x == 1023) bsum[blockIdx.x] = s[1023];
}

__global__ void k_scan2(const int* __restrict__ bsum, int* __restrict__ boff,
                        int* __restrict__ rowptr) {
    if (threadIdx.x == 0 && blockIdx.x == 0) {
        int run = 0;
        for (int b = 0; b < SCAN_NB; ++b) { boff[b] = run; run += bsum[b]; }
        rowptr[NN] = run;  // == NTOT
    }
}

__global__ void k_scan3(int* __restrict__ rowptr, const int* __restrict__ boff) {
    int i = blockIdx.x * 1024 + threadIdx.x;
    if (i < NN) rowptr[i] += boff[blockIdx.x];
}

__global__ void k_self(const float* __restrict__ dinv, const int* __restrict__ rowptr,
                       int* __restrict__ cursor, int* __restrict__ csrc,
                       float* __restrict__ cnorm) {
    int n = blockIdx.x * blockDim.x + threadIdx.x;
    if (n < NN) {
        int pos = rowptr[n] + atomicAdd(&cursor[n], 1);
        csrc[pos] = n;
        float dv = dinv[n];
        cnorm[pos] = dv * dv;
    }
}

__global__ void k_fill(const int* __restrict__ src, const int* __restrict__ dst,
                       const float* __restrict__ dinv, const int* __restrict__ rowptr,
                       int* __restrict__ cursor, int* __restrict__ csrc,
                       float* __restrict__ cnorm) {
    int e = blockIdx.x * blockDim.x + threadIdx.x;
    if (e < NE) {
        int s = src[e], dd = dst[e];
        int pos = rowptr[dd] + atomicAdd(&cursor[dd], 1);
        csrc[pos] = s;
        cnorm[pos] = dinv[s] * dinv[dd];
    }
}

// h[64-row tile] = xnorm @ W ; xnorm = apply ? x*scale+shift : x  (per-feature affine = fused BN)
__launch_bounds__(256)
__global__ void k_gemm(const float* __restrict__ xin, const float* __restrict__ W,
                       const float* __restrict__ scale, const float* __restrict__ shift,
                       float* __restrict__ h, int apply) {
    __shared__ __align__(16) float xs[64 * 33];
    __shared__ __align__(16) float ws[32 * 128];
    int tid = threadIdx.x;
    int jt = tid & 31, it = tid >> 5;
    int j0 = jt * 4, r0 = it * 8;
    int rowbase = blockIdx.x * 64;
    float acc[8][4];
#pragma unroll
    for (int m = 0; m < 8; ++m)
#pragma unroll
        for (int q = 0; q < 4; ++q) acc[m][q] = 0.f;

    for (int kt = 0; kt < 128; kt += 32) {
#pragma unroll
        for (int l = 0; l < 8; ++l) {  // x tile 64x32
            int idx = tid + l * 256;
            int r = idx >> 5, c = idx & 31;
            int row = rowbase + r;
            float v = 0.f;
            if (row < NN) {
                v = xin[row * 128 + kt + c];
                if (apply) v = v * scale[kt + c] + shift[kt + c];
            }
            xs[r * 33 + c] = v;
        }
#pragma unroll
        for (int l = 0; l < 16; ++l) {  // W tile 32x128
            int idx = tid + l * 256;
            int r = idx >> 7, c = idx & 127;
            ws[r * 128 + c] = W[(kt + r) * 128 + c];
        }
        __syncthreads();
#pragma unroll 8
        for (int k = 0; k < 32; ++k) {
            float4 w4 = *(const float4*)&ws[k * 128 + j0];
#pragma unroll
            for (int m = 0; m < 8; ++m) {
                float xv = xs[(r0 + m) * 33 + k];
                acc[m][0] += xv * w4.x;
                acc[m][1] += xv * w4.y;
                acc[m][2] += xv * w4.z;
                acc[m][3] += xv * w4.w;
            }
        }
        __syncthreads();
    }
#pragma unroll
    for (int m = 0; m < 8; ++m) {
        int row = rowbase + r0 + m;
        if (row < NN) {
            float4 o;
            o.x = acc[m][0]; o.y = acc[m][1]; o.z = acc[m][2]; o.w = acc[m][3];
            *(float4*)&h[row * 128 + j0] = o;
        }
    }
}

// per-node gather-aggregate + bias + sigmoid + BN stats accumulation.
// 256 threads = 8 groups x 32 lanes; each lane owns 4 features (float4).
__launch_bounds__(256)
__global__ void k_agg(const float* __restrict__ h, const int* __restrict__ rowptr,
                      const int* __restrict__ csrc, const float* __restrict__ cnorm,
                      const float* __restrict__ bias, float* __restrict__ aout,
                      float* __restrict__ gstat) {
    __shared__ float s_sum[128];
    __shared__ float s_ss[128];
    int tid = threadIdx.x;
    int g = tid >> 5, l = tid & 31;
    int j0 = l * 4;
    if (tid < 128) { s_sum[tid] = 0.f; s_ss[tid] = 0.f; }
    __syncthreads();

    float4 bv = *(const float4*)&bias[j0];
    float lsx = 0.f, lsy = 0.f, lsz = 0.f, lsw = 0.f;
    float qsx = 0.f, qsy = 0.f, qsz = 0.f, qsw = 0.f;

    for (int n = blockIdx.x * 8 + g; n < NN; n += gridDim.x * 8) {
        int p = rowptr[n], e = rowptr[n + 1];
        float ax = bv.x, ay = bv.y, az = bv.z, aw = bv.w;
        for (; p + 3 < e; p += 4) {
            int s0 = csrc[p], s1 = csrc[p + 1], s2 = csrc[p + 2], s3 = csrc[p + 3];
            float w0 = cnorm[p], w1 = cnorm[p + 1], w2 = cnorm[p + 2], w3 = cnorm[p + 3];
            float4 h0 = *(const float4*)&h[s0 * 128 + j0];
            float4 h1 = *(const float4*)&h[s1 * 128 + j0];
            float4 h2 = *(const float4*)&h[s2 * 128 + j0];
            float4 h3 = *(const float4*)&h[s3 * 128 + j0];
            ax += w0 * h0.x + w1 * h1.x + w2 * h2.x + w3 * h3.x;
            ay += w0 * h0.y + w1 * h1.y + w2 * h2.y + w3 * h3.y;
            az += w0 * h0.z + w1 * h1.z + w2 * h2.z + w3 * h3.z;
            aw += w0 * h0.w + w1 * h1.w + w2 * h2.w + w3 * h3.w;
        }
        for (; p < e; ++p) {
            int s0 = csrc[p];
            float w0 = cnorm[p];
            float4 h0 = *(const float4*)&h[s0 * 128 + j0];
            ax += w0 * h0.x;
            ay += w0 * h0.y;
            az += w0 * h0.z;
            aw += w0 * h0.w;
        }
        float4 o;
        o.x = 1.0f / (1.0f + __expf(-ax));
        o.y = 1.0f / (1.0f + __expf(-ay));
        o.z = 1.0f / (1.0f + __expf(-az));
        o.w = 1.0f / (1.0f + __expf(-aw));
        *(float4*)&aout[n * 128 + j0] = o;
        lsx += o.x; lsy += o.y; lsz += o.z; lsw += o.w;
        qsx += o.x * o.x; qsy += o.y * o.y; qsz += o.z * o.z; qsw += o.w * o.w;
    }

    atomicAdd(&s_sum[j0 + 0], lsx);
    atomicAdd(&s_sum[j0 + 1], lsy);
    atomicAdd(&s_sum[j0 + 2], lsz);
    atomicAdd(&s_sum[j0 + 3], lsw);
    atomicAdd(&s_ss[j0 + 0], qsx);
    atomicAdd(&s_ss[j0 + 1], qsy);
    atomicAdd(&s_ss[j0 + 2], qsz);
    atomicAdd(&s_ss[j0 + 3], qsw);
    __syncthreads();
    if (tid < 128) atomicAdd(&gstat[tid], s_sum[tid]);
    else atomicAdd(&gstat[tid], s_ss[tid - 128]);
}

__global__ void k_stats(const float* __restrict__ gstat, const float* __restrict__ gamma,
                        const float* __restrict__ beta, float* __restrict__ scale,
                        float* __restrict__ shift) {
    int d = threadIdx.x;  // 128 threads, 1 block
    float s = gstat[d];
    float ss = gstat[128 + d];
    float m = s / (float)NN;
    float v = ss / (float)NN - m * m;
    float rstd = 1.0f / sqrtf(v + BN_EPS);
    float g = gamma[d];
    scale[d] = rstd * g;
    shift[d] = beta[d] - m * rstd * g;
}

// final BN + write x out + segment-pool (batch sorted: flush atomics only at boundaries)
__launch_bounds__(128)
__global__ void k_pool(const float* __restrict__ a2, const float* __restrict__ scale,
                       const float* __restrict__ shift, const int* __restrict__ batch,
                       float* __restrict__ xout, float* __restrict__ pools,
                       int* __restrict__ cntb) {
    int d = threadIdx.x;
    int n0 = blockIdx.x * 64;
    if (n0 >= NN) return;
    int n1 = min(n0 + 64, NN);
    float sc = scale[d], sh = shift[d];
    float accp = 0.f;
    int cl = 0;
    int curb = batch[n0];
    for (int n = n0; n < n1; ++n) {
        int b = batch[n];
        float xv = a2[n * 128 + d] * sc + sh;
        xout[n * 128 + d] = xv;
        if (b != curb) {
            atomicAdd(&pools[curb * 128 + d], accp);
            if (d == 0) atomicAdd(&cntb[curb], cl);
            accp = 0.f;
            cl = 0;
            curb = b;
        }
        accp += xv;
        cl++;
    }
    atomicAdd(&pools[curb * 128 + d], accp);
    if (d == 0) atomicAdd(&cntb[curb], cl);
}

__global__ void k_fin(const float* __restrict__ pools, const int* __restrict__ cntb,
                      float* __restrict__ xpool) {
    int i = blockIdx.x * blockDim.x + threadIdx.x;
    if (i < NBATCH * 128) {
        int b = i >> 7;
        float c = (float)cntb[b];
        xpool[i] = pools[i] / fmaxf(c, 1.0f);
    }
}

extern "C" void kernel_launch(void* const* d_in, const int* in_sizes, int n_in,
                              void* d_out, int out_size, void* d_ws, size_t ws_size,
                              hipStream_t stream) {
    const float* x   = (const float*)d_in[0];
    const int*   ei  = (const int*)d_in[1];
    const int*   bat = (const int*)d_in[2];
    const float* Ws  = (const float*)d_in[3];
    const float* bs  = (const float*)d_in[4];
    const float* gs  = (const float*)d_in[5];
    const float* bts = (const float*)d_in[6];
    float* out = (float*)d_out;

    float* wsf = (float*)d_ws;
    int*   deg    = (int*)wsf + OFF_DEG;
    float* dinv   = wsf + OFF_DINV;
    int*   rowptr = (int*)wsf + OFF_ROWPTR;
    int*   cursor = (int*)wsf + OFF_CURSOR;
    int*   bsum   = (int*)wsf + OFF_BSUM;
    int*   boff   = (int*)wsf + OFF_BOFF;
    int*   csrc   = (int*)wsf + OFF_CSRC;
    float* cnorm  = wsf + OFF_CNORM;
    float* hbuf   = wsf + OFF_H;
    float* abuf   = wsf + OFF_A;
    float* gstat  = wsf + OFF_GSTAT;
    float* scbuf  = wsf + OFF_SC;
    float* shbuf  = wsf + OFF_SH;
    float* pools  = wsf + OFF_POOL;
    int*   cntb   = (int*)wsf + OFF_CNTB;

    const int* srcv = ei;
    const int* dstv = ei + NE;

    hipMemsetAsync(deg, 0, NN * 4, stream);
    hipMemsetAsync(cursor, 0, NN * 4, stream);
    hipMemsetAsync(gstat, 0, 3 * 256 * 4, stream);
    hipMemsetAsync(pools, 0, NBATCH * 128 * 4, stream);
    hipMemsetAsync(cntb, 0, NBATCH * 4, stream);

    k_deg<<<(NE + 255) / 256, 256, 0, stream>>>(dstv, deg);
    k_dinv<<<(NN + 255) / 256, 256, 0, stream>>>(deg, dinv);
    k_scan1<<<SCAN_NB, 1024, 0, stream>>>(deg, rowptr, bsum);
    k_scan2<<<1, 1, 0, stream>>>(bsum, boff, rowptr);
    k_scan3<<<SCAN_NB, 1024, 0, stream>>>(rowptr, boff);
    k_self<<<(NN + 255) / 256, 256, 0, stream>>>(dinv, rowptr, cursor, csrc, cnorm);
    k_fill<<<(NE + 255) / 256, 256, 0, stream>>>(srcv, dstv, dinv, rowptr, cursor, csrc, cnorm);

    for (int l = 0; l < 3; ++l) {
        const float* xin = (l == 0) ? x : abuf;
        k_gemm<<<(NN + 63) / 64, 256, 0, stream>>>(xin, Ws + (size_t)l * 128 * 128,
                                                   scbuf, shbuf, hbuf, l > 0 ? 1 : 0);
        k_agg<<<AGG_BLOCKS, 256, 0, stream>>>(hbuf, rowptr, csrc, cnorm, bs + l * 128,
                                              abuf, gstat + l * 256);
        k_stats<<<1, 128, 0, stream>>>(gstat + l * 256, gs + l * 128, bts + l * 128,
                                       scbuf, shbuf);
    }

    k_pool<<<(NN + 63) / 64, 128, 0, stream>>>(abuf, scbuf, shbuf, bat,
                                               out + NBATCH * 128, pools, cntb);
    k_fin<<<(NBATCH * 128 + 255) / 256, 256, 0, stream>>>(pools, cntb, out);
}

// Round 3
// 835.494 us; speedup vs baseline: 1.7101x; 1.1795x over previous
//
#include <hip/hip_runtime.h>
#include <hip/hip_fp16.h>

#define NN 100000
#define NE 1600000
#define NBATCH 512
#define DIM 128
#define BN_EPS 1e-4f
#define NTOT (NE + NN)
#define AGG_BLOCKS 2048
#define SCAN_NB 98  // ceil(NN/1024)

typedef __attribute__((ext_vector_type(4))) short short4v;
union H4 { short4v s; __half2 h2[2]; };

// ---- workspace layout (units of 4-byte elements, 64-elem aligned) ----
#define OFF_DEG     0u          // NN int
#define OFF_DINV    100032u     // NN f32
#define OFF_ROWPTR  200064u     // NN+1 int
#define OFF_CURSOR  300096u     // NN int
#define OFF_BSUM    400128u     // 128 int
#define OFF_BOFF    400256u     // 128 int
#define OFF_CSRC    400384u     // NTOT int
#define OFF_CNORM   2100416u    // NTOT f32
#define OFF_H       3800448u    // NN*128 __half (uses half the slot)
#define OFF_A       16600448u   // NN*128 f32
#define OFF_GSTAT   29400448u   // 3*256 f32 (per-layer sum/sumsq accumulators)
#define OFF_SC      29924736u   // 128 f32
#define OFF_SH      29924864u   // 128 f32
#define OFF_POOL    29924992u   // 512*128 f32
#define OFF_CNTB    29990528u   // 512 int

__global__ void k_deg(const int* __restrict__ dst, int* __restrict__ deg) {
    int e = blockIdx.x * blockDim.x + threadIdx.x;
    if (e < NE) atomicAdd(&deg[dst[e]], 1);
}

__global__ void k_dinv(const int* __restrict__ deg, float* __restrict__ dinv) {
    int n = blockIdx.x * blockDim.x + threadIdx.x;
    if (n < NN) dinv[n] = 1.0f / sqrtf((float)(deg[n] + 1));
}

__global__ void k_scan1(const int* __restrict__ deg, int* __restrict__ rowptr,
                        int* __restrict__ bsum) {
    __shared__ int s[1024];
    int i = blockIdx.x * 1024 + threadIdx.x;
    int v = (i < NN) ? (deg[i] + 1) : 0;
    s[threadIdx.x] = v;
    __syncthreads();
    for (int off = 1; off < 1024; off <<= 1) {
        int t = (threadIdx.x >= off) ? s[threadIdx.x - off] : 0;
        __syncthreads();
        s[threadIdx.x] += t;
        __syncthreads();
    }
    if (i < NN) rowptr[i] = s[threadIdx.x] - v;  // exclusive scan
    if (threadIdx.x == 1023) bsum[blockIdx.x] = s[1023];
}

__global__ void k_scan2(const int* __restrict__ bsum, int* __restrict__ boff,
                        int* __restrict__ rowptr) {
    if (threadIdx.x == 0 && blockIdx.x == 0) {
        int run = 0;
        for (int b = 0; b < SCAN_NB; ++b) { boff[b] = run; run += bsum[b]; }
        rowptr[NN] = run;  // == NTOT
    }
}

__global__ void k_scan3(int* __restrict__ rowptr, const int* __restrict__ boff) {
    int i = blockIdx.x * 1024 + threadIdx.x;
    if (i < NN) rowptr[i] += boff[blockIdx.x];
}

__global__ void k_self(const float* __restrict__ dinv, const int* __restrict__ rowptr,
                       int* __restrict__ cursor, int* __restrict__ csrc,
                       float* __restrict__ cnorm) {
    int n = blockIdx.x * blockDim.x + threadIdx.x;
    if (n < NN) {
        int pos = rowptr[n] + atomicAdd(&cursor[n], 1);
        csrc[pos] = n;
        float dv = dinv[n];
        cnorm[pos] = dv * dv;
    }
}

__global__ void k_fill(const int* __restrict__ src, const int* __restrict__ dst,
                       const float* __restrict__ dinv, const int* __restrict__ rowptr,
                       int* __restrict__ cursor, int* __restrict__ csrc,
                       float* __restrict__ cnorm) {
    int e = blockIdx.x * blockDim.x + threadIdx.x;
    if (e < NE) {
        int s = src[e], dd = dst[e];
        int pos = rowptr[dd] + atomicAdd(&cursor[dd], 1);
        csrc[pos] = s;
        cnorm[pos] = dinv[s] * dinv[dd];
    }
}

// h[64-row tile] = xnorm @ W ; xnorm = apply ? x*scale+shift : x  (per-feature affine = fused BN)
// output written as fp16.
__launch_bounds__(256)
__global__ void k_gemm(const float* __restrict__ xin, const float* __restrict__ W,
                       const float* __restrict__ scale, const float* __restrict__ shift,
                       __half* __restrict__ h, int apply) {
    __shared__ __align__(16) float xs[64 * 33];
    __shared__ __align__(16) float ws[32 * 128];
    int tid = threadIdx.x;
    int jt = tid & 31, it = tid >> 5;
    int j0 = jt * 4, r0 = it * 8;
    int rowbase = blockIdx.x * 64;
    float acc[8][4];
#pragma unroll
    for (int m = 0; m < 8; ++m)
#pragma unroll
        for (int q = 0; q < 4; ++q) acc[m][q] = 0.f;

    for (int kt = 0; kt < 128; kt += 32) {
#pragma unroll
        for (int l = 0; l < 8; ++l) {  // x tile 64x32
            int idx = tid + l * 256;
            int r = idx >> 5, c = idx & 31;
            int row = rowbase + r;
            float v = 0.f;
            if (row < NN) {
                v = xin[row * 128 + kt + c];
                if (apply) v = v * scale[kt + c] + shift[kt + c];
            }
            xs[r * 33 + c] = v;
        }
#pragma unroll
        for (int l = 0; l < 16; ++l) {  // W tile 32x128
            int idx = tid + l * 256;
            int r = idx >> 7, c = idx & 127;
            ws[r * 128 + c] = W[(kt + r) * 128 + c];
        }
        __syncthreads();
#pragma unroll 8
        for (int k = 0; k < 32; ++k) {
            float4 w4 = *(const float4*)&ws[k * 128 + j0];
#pragma unroll
            for (int m = 0; m < 8; ++m) {
                float xv = xs[(r0 + m) * 33 + k];
                acc[m][0] += xv * w4.x;
                acc[m][1] += xv * w4.y;
                acc[m][2] += xv * w4.z;
                acc[m][3] += xv * w4.w;
            }
        }
        __syncthreads();
    }
#pragma unroll
    for (int m = 0; m < 8; ++m) {
        int row = rowbase + r0 + m;
        if (row < NN) {
            H4 o;
            o.h2[0] = __floats2half2_rn(acc[m][0], acc[m][1]);
            o.h2[1] = __floats2half2_rn(acc[m][2], acc[m][3]);
            *(short4v*)&h[row * 128 + j0] = o.s;
        }
    }
}

// per-node gather-aggregate + bias + sigmoid + BN stats accumulation.
// 256 threads = 8 groups x 32 lanes; each lane owns 4 features (8B fp16 loads).
__launch_bounds__(256)
__global__ void k_agg(const __half* __restrict__ h, const int* __restrict__ rowptr,
                      const int* __restrict__ csrc, const float* __restrict__ cnorm,
                      const float* __restrict__ bias, float* __restrict__ aout,
                      float* __restrict__ gstat) {
    __shared__ float s_sum[128];
    __shared__ float s_ss[128];
    int tid = threadIdx.x;
    int g = tid >> 5, l = tid & 31;
    int j0 = l * 4;
    if (tid < 128) { s_sum[tid] = 0.f; s_ss[tid] = 0.f; }
    __syncthreads();

    float4 bv = *(const float4*)&bias[j0];
    float lsx = 0.f, lsy = 0.f, lsz = 0.f, lsw = 0.f;
    float qsx = 0.f, qsy = 0.f, qsz = 0.f, qsw = 0.f;

    for (int n = blockIdx.x * 8 + g; n < NN; n += gridDim.x * 8) {
        int p = rowptr[n], e = rowptr[n + 1];
        float ax = bv.x, ay = bv.y, az = bv.z, aw = bv.w;
        for (; p + 3 < e; p += 4) {
            int s0 = csrc[p], s1 = csrc[p + 1], s2 = csrc[p + 2], s3 = csrc[p + 3];
            float w0 = cnorm[p], w1 = cnorm[p + 1], w2 = cnorm[p + 2], w3 = cnorm[p + 3];
            H4 r0; r0.s = *(const short4v*)&h[s0 * 128 + j0];
            H4 r1; r1.s = *(const short4v*)&h[s1 * 128 + j0];
            H4 r2; r2.s = *(const short4v*)&h[s2 * 128 + j0];
            H4 r3; r3.s = *(const short4v*)&h[s3 * 128 + j0];
            float2 a0 = __half22float2(r0.h2[0]), b0 = __half22float2(r0.h2[1]);
            float2 a1 = __half22float2(r1.h2[0]), b1 = __half22float2(r1.h2[1]);
            float2 a2 = __half22float2(r2.h2[0]), b2 = __half22float2(r2.h2[1]);
            float2 a3 = __half22float2(r3.h2[0]), b3 = __half22float2(r3.h2[1]);
            ax += w0 * a0.x + w1 * a1.x + w2 * a2.x + w3 * a3.x;
            ay += w0 * a0.y + w1 * a1.y + w2 * a2.y + w3 * a3.y;
            az += w0 * b0.x + w1 * b1.x + w2 * b2.x + w3 * b3.x;
            aw += w0 * b0.y + w1 * b1.y + w2 * b2.y + w3 * b3.y;
        }
        for (; p < e; ++p) {
            int s0 = csrc[p];
            float w0 = cnorm[p];
            H4 r0; r0.s = *(const short4v*)&h[s0 * 128 + j0];
            float2 a0 = __half22float2(r0.h2[0]), b0 = __half22float2(r0.h2[1]);
            ax += w0 * a0.x;
            ay += w0 * a0.y;
            az += w0 * b0.x;
            aw += w0 * b0.y;
        }
        float4 o;
        o.x = 1.0f / (1.0f + __expf(-ax));
        o.y = 1.0f / (1.0f + __expf(-ay));
        o.z = 1.0f / (1.0f + __expf(-az));
        o.w = 1.0f / (1.0f + __expf(-aw));
        *(float4*)&aout[n * 128 + j0] = o;
        lsx += o.x; lsy += o.y; lsz += o.z; lsw += o.w;
        qsx += o.x * o.x; qsy += o.y * o.y; qsz += o.z * o.z; qsw += o.w * o.w;
    }

    atomicAdd(&s_sum[j0 + 0], lsx);
    atomicAdd(&s_sum[j0 + 1], lsy);
    atomicAdd(&s_sum[j0 + 2], lsz);
    atomicAdd(&s_sum[j0 + 3], lsw);
    atomicAdd(&s_ss[j0 + 0], qsx);
    atomicAdd(&s_ss[j0 + 1], qsy);
    atomicAdd(&s_ss[j0 + 2], qsz);
    atomicAdd(&s_ss[j0 + 3], qsw);
    __syncthreads();
    if (tid < 128) atomicAdd(&gstat[tid], s_sum[tid]);
    else atomicAdd(&gstat[tid], s_ss[tid - 128]);
}

__global__ void k_stats(const float* __restrict__ gstat, const float* __restrict__ gamma,
                        const float* __restrict__ beta, float* __restrict__ scale,
                        float* __restrict__ shift) {
    int d = threadIdx.x;  // 128 threads, 1 block
    float s = gstat[d];
    float ss = gstat[128 + d];
    float m = s / (float)NN;
    float v = ss / (float)NN - m * m;
    float rstd = 1.0f / sqrtf(v + BN_EPS);
    float g = gamma[d];
    scale[d] = rstd * g;
    shift[d] = beta[d] - m * rstd * g;
}

// final BN + write x out + segment-pool (batch sorted: flush atomics only at boundaries)
__launch_bounds__(128)
__global__ void k_pool(const float* __restrict__ a2, const float* __restrict__ scale,
                       const float* __restrict__ shift, const int* __restrict__ batch,
                       float* __restrict__ xout, float* __restrict__ pools,
                       int* __restrict__ cntb) {
    int d = threadIdx.x;
    int n0 = blockIdx.x * 64;
    if (n0 >= NN) return;
    int n1 = min(n0 + 64, NN);
    float sc = scale[d], sh = shift[d];
    float accp = 0.f;
    int cl = 0;
    int curb = batch[n0];
    for (int n = n0; n < n1; ++n) {
        int b = batch[n];
        float xv = a2[n * 128 + d] * sc + sh;
        xout[n * 128 + d] = xv;
        if (b != curb) {
            atomicAdd(&pools[curb * 128 + d], accp);
            if (d == 0) atomicAdd(&cntb[curb], cl);
            accp = 0.f;
            cl = 0;
            curb = b;
        }
        accp += xv;
        cl++;
    }
    atomicAdd(&pools[curb * 128 + d], accp);
    if (d == 0) atomicAdd(&cntb[curb], cl);
}

__global__ void k_fin(const float* __restrict__ pools, const int* __restrict__ cntb,
                      float* __restrict__ xpool) {
    int i = blockIdx.x * blockDim.x + threadIdx.x;
    if (i < NBATCH * 128) {
        int b = i >> 7;
        float c = (float)cntb[b];
        xpool[i] = pools[i] / fmaxf(c, 1.0f);
    }
}

extern "C" void kernel_launch(void* const* d_in, const int* in_sizes, int n_in,
                              void* d_out, int out_size, void* d_ws, size_t ws_size,
                              hipStream_t stream) {
    const float* x   = (const float*)d_in[0];
    const int*   ei  = (const int*)d_in[1];
    const int*   bat = (const int*)d_in[2];
    const float* Ws  = (const float*)d_in[3];
    const float* bs  = (const float*)d_in[4];
    const float* gs  = (const float*)d_in[5];
    const float* bts = (const float*)d_in[6];
    float* out = (float*)d_out;

    float* wsf = (float*)d_ws;
    int*   deg    = (int*)wsf + OFF_DEG;
    float* dinv   = wsf + OFF_DINV;
    int*   rowptr = (int*)wsf + OFF_ROWPTR;
    int*   cursor = (int*)wsf + OFF_CURSOR;
    int*   bsum   = (int*)wsf + OFF_BSUM;
    int*   boff   = (int*)wsf + OFF_BOFF;
    int*   csrc   = (int*)wsf + OFF_CSRC;
    float* cnorm  = wsf + OFF_CNORM;
    __half* hbuf  = (__half*)(wsf + OFF_H);
    float* abuf   = wsf + OFF_A;
    float* gstat  = wsf + OFF_GSTAT;
    float* scbuf  = wsf + OFF_SC;
    float* shbuf  = wsf + OFF_SH;
    float* pools  = wsf + OFF_POOL;
    int*   cntb   = (int*)wsf + OFF_CNTB;

    const int* srcv = ei;
    const int* dstv = ei + NE;

    hipMemsetAsync(deg, 0, NN * 4, stream);
    hipMemsetAsync(cursor, 0, NN * 4, stream);
    hipMemsetAsync(gstat, 0, 3 * 256 * 4, stream);
    hipMemsetAsync(pools, 0, NBATCH * 128 * 4, stream);
    hipMemsetAsync(cntb, 0, NBATCH * 4, stream);

    k_deg<<<(NE + 255) / 256, 256, 0, stream>>>(dstv, deg);
    k_dinv<<<(NN + 255) / 256, 256, 0, stream>>>(deg, dinv);
    k_scan1<<<SCAN_NB, 1024, 0, stream>>>(deg, rowptr, bsum);
    k_scan2<<<1, 1, 0, stream>>>(bsum, boff, rowptr);
    k_scan3<<<SCAN_NB, 1024, 0, stream>>>(rowptr, boff);
    k_self<<<(NN + 255) / 256, 256, 0, stream>>>(dinv, rowptr, cursor, csrc, cnorm);
    k_fill<<<(NE + 255) / 256, 256, 0, stream>>>(srcv, dstv, dinv, rowptr, cursor, csrc, cnorm);

    for (int l = 0; l < 3; ++l) {
        const float* xin = (l == 0) ? x : abuf;
        k_gemm<<<(NN + 63) / 64, 256, 0, stream>>>(xin, Ws + (size_t)l * 128 * 128,
                                                   scbuf, shbuf, hbuf, l > 0 ? 1 : 0);
        k_agg<<<AGG_BLOCKS, 256, 0, stream>>>(hbuf, rowptr, csrc, cnorm, bs + l * 128,
                                              abuf, gstat + l * 256);
        k_stats<<<1, 128, 0, stream>>>(gstat + l * 256, gs + l * 128, bts + l * 128,
                                       scbuf, shbuf);
    }

    k_pool<<<(NN + 63) / 64, 128, 0, stream>>>(abuf, scbuf, shbuf, bat,
                                               out + NBATCH * 128, pools, cntb);
    k_fin<<<(NBATCH * 128 + 255) / 256, 256, 0, stream>>>(pools, cntb, out);
}

// Round 5
// 833.201 us; speedup vs baseline: 1.7149x; 1.0028x over previous
//
#include <hip/hip_runtime.h>
#include <hip/hip_fp16.h>

#define NN 100000
#define NE 1600000
#define NBATCH 512
#define DIM 128
#define BN_EPS 1e-4f
#define NTOT (NE + NN)
#define AGG_BLOCKS 2048
#define SCAN_NB 98  // ceil(NN/1024)

typedef __attribute__((ext_vector_type(4))) short short4v;
typedef __attribute__((ext_vector_type(2))) int int2v;
union H4 { short4v s; __half2 h2[2]; };

// ---- workspace layout (units of 4-byte elements) ----
#define OFF_DEG     0u          // NN int
#define OFF_DINV    100032u     // NN f32
#define OFF_ROWPTR  200064u     // NN+1 int
#define OFF_BSUM    400128u     // 128 int
#define OFF_BOFF    400256u     // 128 int
#define OFF_CPACK   400384u     // NTOT int2v (packed {src, norm}) -> 3.4M units, ends 3800384
#define OFF_H       3800448u    // NN*128 __half = 6.4M units, ends 10200448
#define OFF_SLOT    10400896u   // NE int (slot of edge within its dst row), ends 12000896
#define OFF_A       16600448u   // NN*128 __half = 6.4M units
#define OFF_GSTAT   29400448u   // 3*256 f32 (per-layer sum/sumsq accumulators)
#define OFF_SC      29924736u   // 128 f32
#define OFF_SH      29924864u   // 128 f32
#define OFF_POOL    29924992u   // 512*128 f32
#define OFF_CNTB    29990528u   // 512 int

__global__ void k_deg(const int* __restrict__ dst, int* __restrict__ deg,
                      int* __restrict__ slot) {
    int e = blockIdx.x * blockDim.x + threadIdx.x;
    if (e < NE) slot[e] = atomicAdd(&deg[dst[e]], 1);
}

__global__ void k_dinv(const int* __restrict__ deg, float* __restrict__ dinv) {
    int n = blockIdx.x * blockDim.x + threadIdx.x;
    if (n < NN) dinv[n] = 1.0f / sqrtf((float)(deg[n] + 1));
}

__global__ void k_scan1(const int* __restrict__ deg, int* __restrict__ rowptr,
                        int* __restrict__ bsum) {
    __shared__ int s[1024];
    int i = blockIdx.x * 1024 + threadIdx.x;
    int v = (i < NN) ? (deg[i] + 1) : 0;
    s[threadIdx.x] = v;
    __syncthreads();
    for (int off = 1; off < 1024; off <<= 1) {
        int t = (threadIdx.x >= off) ? s[threadIdx.x - off] : 0;
        __syncthreads();
        s[threadIdx.x] += t;
        __syncthreads();
    }
    if (i < NN) rowptr[i] = s[threadIdx.x] - v;  // exclusive scan
    if (threadIdx.x == 1023) bsum[blockIdx.x] = s[1023];
}

__global__ void k_scan2(const int* __restrict__ bsum, int* __restrict__ boff,
                        int* __restrict__ rowptr) {
    if (threadIdx.x == 0 && blockIdx.x == 0) {
        int run = 0;
        for (int b = 0; b < SCAN_NB; ++b) { boff[b] = run; run += bsum[b]; }
        rowptr[NN] = run;  // == NTOT
    }
}

__global__ void k_scan3(int* __restrict__ rowptr, const int* __restrict__ boff) {
    int i = blockIdx.x * 1024 + threadIdx.x;
    if (i < NN) rowptr[i] += boff[blockIdx.x];
}

// self-loop record at rowptr[n]; no atomics
__global__ void k_self(const float* __restrict__ dinv, const int* __restrict__ rowptr,
                       int2v* __restrict__ cpack) {
    int n = blockIdx.x * blockDim.x + threadIdx.x;
    if (n < NN) {
        float dv = dinv[n];
        int2v p;
        p.x = n;
        p.y = __float_as_int(dv * dv);
        cpack[rowptr[n]] = p;
    }
}

// edge records at rowptr[dst]+1+slot; no atomics, single 8B packed store
__global__ void k_fill(const int* __restrict__ src, const int* __restrict__ dst,
                       const int* __restrict__ slot, const float* __restrict__ dinv,
                       const int* __restrict__ rowptr, int2v* __restrict__ cpack) {
    int e = blockIdx.x * blockDim.x + threadIdx.x;
    if (e < NE) {
        int s = src[e], dd = dst[e];
        int pos = rowptr[dd] + 1 + slot[e];
        int2v p;
        p.x = s;
        p.y = __float_as_int(dinv[s] * dinv[dd]);
        cpack[pos] = p;
    }
}

// h[64-row tile] = xnorm @ W ; xnorm = apply ? x*scale+shift : x  (fused BN affine)
// templated input dtype (f32 layer 0, fp16 layers 1-2); output fp16.
template <typename T>
__launch_bounds__(256)
__global__ void k_gemm(const T* __restrict__ xin, const float* __restrict__ W,
                       const float* __restrict__ scale, const float* __restrict__ shift,
                       __half* __restrict__ h, int apply) {
    __shared__ __align__(16) float xs[64 * 33];
    __shared__ __align__(16) float ws[32 * 128];
    int tid = threadIdx.x;
    int jt = tid & 31, it = tid >> 5;
    int j0 = jt * 4, r0 = it * 8;
    int rowbase = blockIdx.x * 64;
    float acc[8][4];
#pragma unroll
    for (int m = 0; m < 8; ++m)
#pragma unroll
        for (int q = 0; q < 4; ++q) acc[m][q] = 0.f;

    for (int kt = 0; kt < 128; kt += 32) {
#pragma unroll
        for (int l = 0; l < 8; ++l) {  // x tile 64x32
            int idx = tid + l * 256;
            int r = idx >> 5, c = idx & 31;
            int row = rowbase + r;
            float v = 0.f;
            if (row < NN) {
                v = (float)xin[row * 128 + kt + c];
                if (apply) v = v * scale[kt + c] + shift[kt + c];
            }
            xs[r * 33 + c] = v;
        }
#pragma unroll
        for (int l = 0; l < 16; ++l) {  // W tile 32x128
            int idx = tid + l * 256;
            int r = idx >> 7, c = idx & 127;
            ws[r * 128 + c] = W[(kt + r) * 128 + c];
        }
        __syncthreads();
#pragma unroll 8
        for (int k = 0; k < 32; ++k) {
            float4 w4 = *(const float4*)&ws[k * 128 + j0];
#pragma unroll
            for (int m = 0; m < 8; ++m) {
                float xv = xs[(r0 + m) * 33 + k];
                acc[m][0] += xv * w4.x;
                acc[m][1] += xv * w4.y;
                acc[m][2] += xv * w4.z;
                acc[m][3] += xv * w4.w;
            }
        }
        __syncthreads();
    }
#pragma unroll
    for (int m = 0; m < 8; ++m) {
        int row = rowbase + r0 + m;
        if (row < NN) {
            H4 o;
            o.h2[0] = __floats2half2_rn(acc[m][0], acc[m][1]);
            o.h2[1] = __floats2half2_rn(acc[m][2], acc[m][3]);
            *(short4v*)&h[row * 128 + j0] = o.s;
        }
    }
}

// per-node gather-aggregate + bias + sigmoid + BN stats accumulation.
// 256 threads = 8 groups x 32 lanes; each lane owns 4 features (8B fp16 loads).
__launch_bounds__(256)
__global__ void k_agg(const __half* __restrict__ h, const int* __restrict__ rowptr,
                      const int2v* __restrict__ cpack, const float* __restrict__ bias,
                      __half* __restrict__ aout, float* __restrict__ gstat) {
    __shared__ float s_sum[128];
    __shared__ float s_ss[128];
    int tid = threadIdx.x;
    int g = tid >> 5, l = tid & 31;
    int j0 = l * 4;
    if (tid < 128) { s_sum[tid] = 0.f; s_ss[tid] = 0.f; }
    __syncthreads();

    float4 bv = *(const float4*)&bias[j0];
    float lsx = 0.f, lsy = 0.f, lsz = 0.f, lsw = 0.f;
    float qsx = 0.f, qsy = 0.f, qsz = 0.f, qsw = 0.f;

    for (int n = blockIdx.x * 8 + g; n < NN; n += gridDim.x * 8) {
        int p = rowptr[n], e = rowptr[n + 1];
        float ax = bv.x, ay = bv.y, az = bv.z, aw = bv.w;
        for (; p + 7 < e; p += 8) {
            int2v c0 = __builtin_nontemporal_load(&cpack[p + 0]);
            int2v c1 = __builtin_nontemporal_load(&cpack[p + 1]);
            int2v c2 = __builtin_nontemporal_load(&cpack[p + 2]);
            int2v c3 = __builtin_nontemporal_load(&cpack[p + 3]);
            int2v c4 = __builtin_nontemporal_load(&cpack[p + 4]);
            int2v c5 = __builtin_nontemporal_load(&cpack[p + 5]);
            int2v c6 = __builtin_nontemporal_load(&cpack[p + 6]);
            int2v c7 = __builtin_nontemporal_load(&cpack[p + 7]);
            H4 r0; r0.s = *(const short4v*)&h[c0.x * 128 + j0];
            H4 r1; r1.s = *(const short4v*)&h[c1.x * 128 + j0];
            H4 r2; r2.s = *(const short4v*)&h[c2.x * 128 + j0];
            H4 r3; r3.s = *(const short4v*)&h[c3.x * 128 + j0];
            H4 r4; r4.s = *(const short4v*)&h[c4.x * 128 + j0];
            H4 r5; r5.s = *(const short4v*)&h[c5.x * 128 + j0];
            H4 r6; r6.s = *(const short4v*)&h[c6.x * 128 + j0];
            H4 r7; r7.s = *(const short4v*)&h[c7.x * 128 + j0];
            float w0 = __int_as_float(c0.y), w1 = __int_as_float(c1.y);
            float w2 = __int_as_float(c2.y), w3 = __int_as_float(c3.y);
            float w4 = __int_as_float(c4.y), w5 = __int_as_float(c5.y);
            float w6 = __int_as_float(c6.y), w7 = __int_as_float(c7.y);
            float2 a0 = __half22float2(r0.h2[0]), b0 = __half22float2(r0.h2[1]);
            float2 a1 = __half22float2(r1.h2[0]), b1 = __half22float2(r1.h2[1]);
            float2 a2 = __half22float2(r2.h2[0]), b2 = __half22float2(r2.h2[1]);
            float2 a3 = __half22float2(r3.h2[0]), b3 = __half22float2(r3.h2[1]);
            float2 a4 = __half22float2(r4.h2[0]), b4 = __half22float2(r4.h2[1]);
            float2 a5 = __half22float2(r5.h2[0]), b5 = __half22float2(r5.h2[1]);
            float2 a6 = __half22float2(r6.h2[0]), b6 = __half22float2(r6.h2[1]);
            float2 a7 = __half22float2(r7.h2[0]), b7 = __half22float2(r7.h2[1]);
            ax += w0 * a0.x + w1 * a1.x + w2 * a2.x + w3 * a3.x
                + w4 * a4.x + w5 * a5.x + w6 * a6.x + w7 * a7.x;
            ay += w0 * a0.y + w1 * a1.y + w2 * a2.y + w3 * a3.y
                + w4 * a4.y + w5 * a5.y + w6 * a6.y + w7 * a7.y;
            az += w0 * b0.x + w1 * b1.x + w2 * b2.x + w3 * b3.x
                + w4 * b4.x + w5 * b5.x + w6 * b6.x + w7 * b7.x;
            aw += w0 * b0.y + w1 * b1.y + w2 * b2.y + w3 * b3.y
                + w4 * b4.y + w5 * b5.y + w6 * b6.y + w7 * b7.y;
        }
        for (; p + 3 < e; p += 4) {
            int2v c0 = __builtin_nontemporal_load(&cpack[p + 0]);
            int2v c1 = __builtin_nontemporal_load(&cpack[p + 1]);
            int2v c2 = __builtin_nontemporal_load(&cpack[p + 2]);
            int2v c3 = __builtin_nontemporal_load(&cpack[p + 3]);
            H4 r0; r0.s = *(const short4v*)&h[c0.x * 128 + j0];
            H4 r1; r1.s = *(const short4v*)&h[c1.x * 128 + j0];
            H4 r2; r2.s = *(const short4v*)&h[c2.x * 128 + j0];
            H4 r3; r3.s = *(const short4v*)&h[c3.x * 128 + j0];
            float w0 = __int_as_float(c0.y), w1 = __int_as_float(c1.y);
            float w2 = __int_as_float(c2.y), w3 = __int_as_float(c3.y);
            float2 a0 = __half22float2(r0.h2[0]), b0 = __half22float2(r0.h2[1]);
            float2 a1 = __half22float2(r1.h2[0]), b1 = __half22float2(r1.h2[1]);
            float2 a2 = __half22float2(r2.h2[0]), b2 = __half22float2(r2.h2[1]);
            float2 a3 = __half22float2(r3.h2[0]), b3 = __half22float2(r3.h2[1]);
            ax += w0 * a0.x + w1 * a1.x + w2 * a2.x + w3 * a3.x;
            ay += w0 * a0.y + w1 * a1.y + w2 * a2.y + w3 * a3.y;
            az += w0 * b0.x + w1 * b1.x + w2 * b2.x + w3 * b3.x;
            aw += w0 * b0.y + w1 * b1.y + w2 * b2.y + w3 * b3.y;
        }
        for (; p < e; ++p) {
            int2v c0 = __builtin_nontemporal_load(&cpack[p]);
            H4 r0; r0.s = *(const short4v*)&h[c0.x * 128 + j0];
            float w0 = __int_as_float(c0.y);
            float2 a0 = __half22float2(r0.h2[0]), b0 = __half22float2(r0.h2[1]);
            ax += w0 * a0.x;
            ay += w0 * a0.y;
            az += w0 * b0.x;
            aw += w0 * b0.y;
        }
        float ox = 1.0f / (1.0f + __expf(-ax));
        float oy = 1.0f / (1.0f + __expf(-ay));
        float oz = 1.0f / (1.0f + __expf(-az));
        float ow = 1.0f / (1.0f + __expf(-aw));
        H4 o;
        o.h2[0] = __floats2half2_rn(ox, oy);
        o.h2[1] = __floats2half2_rn(oz, ow);
        __builtin_nontemporal_store(o.s, (short4v*)&aout[n * 128 + j0]);
        lsx += ox; lsy += oy; lsz += oz; lsw += ow;
        qsx += ox * ox; qsy += oy * oy; qsz += oz * oz; qsw += ow * ow;
    }

    atomicAdd(&s_sum[j0 + 0], lsx);
    atomicAdd(&s_sum[j0 + 1], lsy);
    atomicAdd(&s_sum[j0 + 2], lsz);
    atomicAdd(&s_sum[j0 + 3], lsw);
    atomicAdd(&s_ss[j0 + 0], qsx);
    atomicAdd(&s_ss[j0 + 1], qsy);
    atomicAdd(&s_ss[j0 + 2], qsz);
    atomicAdd(&s_ss[j0 + 3], qsw);
    __syncthreads();
    if (tid < 128) atomicAdd(&gstat[tid], s_sum[tid]);
    else atomicAdd(&gstat[tid], s_ss[tid - 128]);
}

__global__ void k_stats(const float* __restrict__ gstat, const float* __restrict__ gamma,
                        const float* __restrict__ beta, float* __restrict__ scale,
                        float* __restrict__ shift) {
    int d = threadIdx.x;  // 128 threads, 1 block
    float s = gstat[d];
    float ss = gstat[128 + d];
    float m = s / (float)NN;
    float v = ss / (float)NN - m * m;
    float rstd = 1.0f / sqrtf(v + BN_EPS);
    float g = gamma[d];
    scale[d] = rstd * g;
    shift[d] = beta[d] - m * rstd * g;
}

// final BN + write x out + segment-pool (batch sorted: flush atomics only at boundaries)
__launch_bounds__(128)
__global__ void k_pool(const __half* __restrict__ a2, const float* __restrict__ scale,
                       const float* __restrict__ shift, const int* __restrict__ batch,
                       float* __restrict__ xout, float* __restrict__ pools,
                       int* __restrict__ cntb) {
    int d = threadIdx.x;
    int n0 = blockIdx.x * 64;
    if (n0 >= NN) return;
    int n1 = min(n0 + 64, NN);
    float sc = scale[d], sh = shift[d];
    float accp = 0.f;
    int cl = 0;
    int curb = batch[n0];
    for (int n = n0; n < n1; ++n) {
        int b = batch[n];
        float xv = __half2float(a2[n * 128 + d]) * sc + sh;
        xout[n * 128 + d] = xv;
        if (b != curb) {
            atomicAdd(&pools[curb * 128 + d], accp);
            if (d == 0) atomicAdd(&cntb[curb], cl);
            accp = 0.f;
            cl = 0;
            curb = b;
        }
        accp += xv;
        cl++;
    }
    atomicAdd(&pools[curb * 128 + d], accp);
    if (d == 0) atomicAdd(&cntb[curb], cl);
}

__global__ void k_fin(const float* __restrict__ pools, const int* __restrict__ cntb,
                      float* __restrict__ xpool) {
    int i = blockIdx.x * blockDim.x + threadIdx.x;
    if (i < NBATCH * 128) {
        int b = i >> 7;
        float c = (float)cntb[b];
        xpool[i] = pools[i] / fmaxf(c, 1.0f);
    }
}

extern "C" void kernel_launch(void* const* d_in, const int* in_sizes, int n_in,
                              void* d_out, int out_size, void* d_ws, size_t ws_size,
                              hipStream_t stream) {
    const float* x   = (const float*)d_in[0];
    const int*   ei  = (const int*)d_in[1];
    const int*   bat = (const int*)d_in[2];
    const float* Ws  = (const float*)d_in[3];
    const float* bs  = (const float*)d_in[4];
    const float* gs  = (const float*)d_in[5];
    const float* bts = (const float*)d_in[6];
    float* out = (float*)d_out;

    float* wsf = (float*)d_ws;
    int*   deg    = (int*)wsf + OFF_DEG;
    float* dinv   = wsf + OFF_DINV;
    int*   rowptr = (int*)wsf + OFF_ROWPTR;
    int*   bsum   = (int*)wsf + OFF_BSUM;
    int*   boff   = (int*)wsf + OFF_BOFF;
    int2v* cpack  = (int2v*)(wsf + OFF_CPACK);
    __half* hbuf  = (__half*)(wsf + OFF_H);
    int*   slot   = (int*)wsf + OFF_SLOT;
    __half* abuf  = (__half*)(wsf + OFF_A);
    float* gstat  = wsf + OFF_GSTAT;
    float* scbuf  = wsf + OFF_SC;
    float* shbuf  = wsf + OFF_SH;
    float* pools  = wsf + OFF_POOL;
    int*   cntb   = (int*)wsf + OFF_CNTB;

    const int* srcv = ei;
    const int* dstv = ei + NE;

    hipMemsetAsync(deg, 0, NN * 4, stream);
    hipMemsetAsync(gstat, 0, 3 * 256 * 4, stream);
    hipMemsetAsync(pools, 0, NBATCH * 128 * 4, stream);
    hipMemsetAsync(cntb, 0, NBATCH * 4, stream);

    k_deg<<<(NE + 255) / 256, 256, 0, stream>>>(dstv, deg, slot);
    k_dinv<<<(NN + 255) / 256, 256, 0, stream>>>(deg, dinv);
    k_scan1<<<SCAN_NB, 1024, 0, stream>>>(deg, rowptr, bsum);
    k_scan2<<<1, 1, 0, stream>>>(bsum, boff, rowptr);
    k_scan3<<<SCAN_NB, 1024, 0, stream>>>(rowptr, boff);
    k_self<<<(NN + 255) / 256, 256, 0, stream>>>(dinv, rowptr, cpack);
    k_fill<<<(NE + 255) / 256, 256, 0, stream>>>(srcv, dstv, slot, dinv, rowptr, cpack);

    for (int l = 0; l < 3; ++l) {
        const float* Wl = Ws + (size_t)l * 128 * 128;
        if (l == 0)
            k_gemm<float><<<(NN + 63) / 64, 256, 0, stream>>>(x, Wl, scbuf, shbuf, hbuf, 0);
        else
            k_gemm<__half><<<(NN + 63) / 64, 256, 0, stream>>>(abuf, Wl, scbuf, shbuf, hbuf, 1);
        k_agg<<<AGG_BLOCKS, 256, 0, stream>>>(hbuf, rowptr, cpack, bs + l * 128,
                                              abuf, gstat + l * 256);
        k_stats<<<1, 128, 0, stream>>>(gstat + l * 256, gs + l * 128, bts + l * 128,
                                       scbuf, shbuf);
    }

    k_pool<<<(NN + 63) / 64, 128, 0, stream>>>(abuf, scbuf, shbuf, bat,
                                               out + NBATCH * 128, pools, cntb);
    k_fin<<<(NBATCH * 128 + 255) / 256, 256, 0, stream>>>(pools, cntb, out);
}